// Round 4
// baseline (621.065 us; speedup 1.0000x reference)
//
#include <hip/hip_runtime.h>

// Capsule routing: B=256, J=2, N=6912, E=16, D=8, 2 routing iters. All fp32.
// R14: R13 post-mortem: cooperative grid.sync costs ~100us each on gfx950
// (kfused 450us @ VALUBusy 8% = parked in barriers) -> revert to 4 launches.
// R12 analysis: kpass at 4 blocks/CU is latency-bound (VALUBusy 21%): per-iter
// issue ~190cyc x 4 waves/SIMD = 760cyc < ~900cyc HBM latency. Fix: 6 blocks/CU
// (CGX=384, NBT=18 even, LDS 18.4KB, launch_bounds(256,6)) -> 6x190=1140cyc.
// Staging in 3+2 register rounds (<=12 live, no R12 spill). kred split-K by 2
// (64 blocks, 192 chunks/thread + LDS combine) to halve its latency chain.
#define B_ 256
#define J_ 2
#define N_ 6912
#define E_ 16
#define D_ 8
#define NBT 18                 // n per block tile (even)
#define CGX 384                // grid (CGX,4) = 1536 blocks = 6/CU
#define TOT4 (J_*NBT*32)       // float4 units in W tile = 1152 (18432 B)
#define BSTR (4*N_*D_)         // float stride between a thread's consecutive b's

// sum over the 16-lane row (e-lanes sharing b_lo), pure VALU/DPP:
__device__ __forceinline__ float dpp_row_add16(float v){
  v += __int_as_float(__builtin_amdgcn_update_dpp(0, __float_as_int(v), 0xB1,  0xF, 0xF, true)); // xor 1
  v += __int_as_float(__builtin_amdgcn_update_dpp(0, __float_as_int(v), 0x4E,  0xF, 0xF, true)); // xor 2
  v += __int_as_float(__builtin_amdgcn_update_dpp(0, __float_as_int(v), 0x141, 0xF, 0xF, true)); // xor 7
  v += __int_as_float(__builtin_amdgcn_update_dpp(0, __float_as_int(v), 0x140, 0xF, 0xF, true)); // xor 15
  return v;
}

__device__ __forceinline__ void ldx(const float* __restrict__ xp, int ni,
                                    float4 (&xa)[4], float4 (&xb)[4]){
  #pragma unroll
  for (int k=0;k<4;++k){
    xa[k] = *(const float4*)(xp + (size_t)k*BSTR + ni*8);
    xb[k] = *(const float4*)(xp + (size_t)k*BSTR + ni*8 + 4);
  }
}

__device__ __forceinline__ void body1(const float4* __restrict__ smem4, int ni,
                                      int sA, int sB,
                                      const float4 (&xa)[4], const float4 (&xb)[4],
                                      float (&acc0)[4], float (&acc1)[4]){
  const float4 wa0 = smem4[ni*32 + sA];
  const float4 wb0 = smem4[ni*32 + sB];
  const float4 wa1 = smem4[(NBT + ni)*32 + sA];
  const float4 wb1 = smem4[(NBT + ni)*32 + sB];
  #pragma unroll
  for (int k=0;k<4;++k){
    float a0 = acc0[k], a1 = acc1[k];
    a0 = fmaf(wa0.x, xa[k].x, a0); a0 = fmaf(wa0.y, xa[k].y, a0);
    a0 = fmaf(wa0.z, xa[k].z, a0); a0 = fmaf(wa0.w, xa[k].w, a0);
    a0 = fmaf(wb0.x, xb[k].x, a0); a0 = fmaf(wb0.y, xb[k].y, a0);
    a0 = fmaf(wb0.z, xb[k].z, a0); a0 = fmaf(wb0.w, xb[k].w, a0);
    a1 = fmaf(wa1.x, xa[k].x, a1); a1 = fmaf(wa1.y, xa[k].y, a1);
    a1 = fmaf(wa1.z, xa[k].z, a1); a1 = fmaf(wa1.w, xa[k].w, a1);
    a1 = fmaf(wb1.x, xb[k].x, a1); a1 = fmaf(wb1.y, xb[k].y, a1);
    a1 = fmaf(wb1.z, xb[k].z, a1); a1 = fmaf(wb1.w, xb[k].w, a1);
    acc0[k] = a0; acc1[k] = a1;
  }
}

__device__ __forceinline__ void body2(const float4* __restrict__ smem4, int ni,
                                      int sA, int sB,
                                      const float4 (&xa)[4], const float4 (&xb)[4],
                                      const float (&vj0)[4], const float (&vj1)[4],
                                      float (&acc0)[4], float (&acc1)[4]){
  const float4 wa0 = smem4[ni*32 + sA];
  const float4 wb0 = smem4[ni*32 + sB];
  const float4 wa1 = smem4[(NBT + ni)*32 + sA];
  const float4 wb1 = smem4[(NBT + ni)*32 + sB];
  float u0[4], u1[4];
  #pragma unroll
  for (int k=0;k<4;++k){
    float a0, a1;
    a0 = wa0.x*xa[k].x;            a0 = fmaf(wa0.y, xa[k].y, a0);
    a0 = fmaf(wa0.z, xa[k].z, a0); a0 = fmaf(wa0.w, xa[k].w, a0);
    a0 = fmaf(wb0.x, xb[k].x, a0); a0 = fmaf(wb0.y, xb[k].y, a0);
    a0 = fmaf(wb0.z, xb[k].z, a0); a0 = fmaf(wb0.w, xb[k].w, a0);
    a1 = wa1.x*xa[k].x;            a1 = fmaf(wa1.y, xa[k].y, a1);
    a1 = fmaf(wa1.z, xa[k].z, a1); a1 = fmaf(wa1.w, xa[k].w, a1);
    a1 = fmaf(wb1.x, xb[k].x, a1); a1 = fmaf(wb1.y, xb[k].y, a1);
    a1 = fmaf(wb1.z, xb[k].z, a1); a1 = fmaf(wb1.w, xb[k].w, a1);
    u0[k] = a0; u1[k] = a1;
  }
  #pragma unroll
  for (int k=0;k<4;++k){
    const float d  = dpp_row_add16(fmaf(vj1[k], u1[k], -(vj0[k]*u0[k])));
    const float c0 = __builtin_amdgcn_rcpf(1.f + __expf(d));   // softmax over 2 caps
    acc0[k] = fmaf(c0,       u0[k], acc0[k]);
    acc1[k] = fmaf(1.f - c0, u1[k], acc1[k]);
  }
}

// Stage W[j][NBT n][16 e][8 d] -> LDS, XOR-swizzled in 16B units within each
// 32-unit row. 3+2 register rounds (<=12 float4 live; R12's 7-round single
// batch spilled to scratch).
__device__ __forceinline__ void stageW(const float* __restrict__ W, int nb0, int tid,
                                       float* __restrict__ smem){
  {
    float4 buf[3];
    #pragma unroll
    for (int k=0;k<3;++k){
      const int idx = k*256 + tid;
      const int j  = (idx >= NBT*32) ? 1 : 0;
      const int r4 = idx - j*(NBT*32);
      buf[k] = *(const float4*)(W + ((size_t)j*N_ + nb0)*(E_*D_) + (size_t)r4*4);
    }
    #pragma unroll
    for (int k=0;k<3;++k){
      const int idx = k*256 + tid;
      const int u = idx & 31;
      *(float4*)(smem + (size_t)((idx & ~31) | (u ^ (u>>3)))*4) = buf[k];
    }
  }
  {
    float4 buf[2];
    #pragma unroll
    for (int k=0;k<2;++k){
      const int idx = (k+3)*256 + tid;
      if (idx < TOT4){
        const int j  = (idx >= NBT*32) ? 1 : 0;
        const int r4 = idx - j*(NBT*32);
        buf[k] = *(const float4*)(W + ((size_t)j*N_ + nb0)*(E_*D_) + (size_t)r4*4);
      }
    }
    #pragma unroll
    for (int k=0;k<2;++k){
      const int idx = (k+3)*256 + tid;
      if (idx < TOT4){
        const int u = idx & 31;
        *(float4*)(smem + (size_t)((idx & ~31) | (u ^ (u>>3)))*4) = buf[k];
      }
    }
  }
}

// ---------------- main path (4 launches) ----------------

__global__ __launch_bounds__(256, 6) void kpass1(const float* __restrict__ x,
                                                 const float* __restrict__ W,
                                                 float* __restrict__ partial)
{
  __shared__ float smem[TOT4*4];   // 18432 B
  const int tid  = threadIdx.x;
  const int lane = tid & 63;
  const int wv   = __builtin_amdgcn_readfirstlane(tid >> 6);
  const int e    = lane & 15;
  const int blo  = lane >> 4;
  const int nb0  = blockIdx.x * NBT;
  const int b0   = blockIdx.y*64 + wv*16 + blo;
  const float* xp = x + ((size_t)b0*N_ + nb0)*D_;
  const int sA = (e*2)   ^ ((e*2)>>3);
  const int sB = (e*2+1) ^ ((e*2+1)>>3);
  const float4* smem4 = (const float4*)smem;

  stageW(W, nb0, tid, smem);
  float4 xaA[4], xbA[4], xaB[4], xbB[4];
  ldx(xp, 0, xaA, xbA);
  __syncthreads();

  float acc0[4] = {0,0,0,0}, acc1[4] = {0,0,0,0};
  #pragma unroll 1
  for (int ni=0; ni<NBT; ni+=2){
    ldx(xp, ni+1, xaB, xbB);
    body1(smem4, ni,   sA, sB, xaA, xbA, acc0, acc1);
    if (ni+2 < NBT) ldx(xp, ni+2, xaA, xbA);
    body1(smem4, ni+1, sA, sB, xaB, xbB, acc0, acc1);
  }

  float* dst = partial + (size_t)(blockIdx.x*4 + blockIdx.y)*2048
             + (wv*16 + blo)*32 + e;
  #pragma unroll
  for (int k=0;k<4;++k){ dst[k*128] = acc0[k]; dst[k*128+16] = acc1[k]; }
}

__global__ __launch_bounds__(256, 6) void kpass2(const float* __restrict__ x,
                                                 const float* __restrict__ W,
                                                 const float* __restrict__ v1,
                                                 float* __restrict__ partial)
{
  __shared__ float smem[TOT4*4];
  const int tid  = threadIdx.x;
  const int lane = tid & 63;
  const int wv   = __builtin_amdgcn_readfirstlane(tid >> 6);
  const int e    = lane & 15;
  const int blo  = lane >> 4;
  const int nb0  = blockIdx.x * NBT;
  const int b0   = blockIdx.y*64 + wv*16 + blo;
  const float* xp = x + ((size_t)b0*N_ + nb0)*D_;
  const int sA = (e*2)   ^ ((e*2)>>3);
  const int sB = (e*2+1) ^ ((e*2+1)>>3);
  const float4* smem4 = (const float4*)smem;

  stageW(W, nb0, tid, smem);
  float4 xaA[4], xbA[4], xaB[4], xbB[4];
  ldx(xp, 0, xaA, xbA);
  float vj0[4], vj1[4];
  #pragma unroll
  for (int k=0;k<4;++k){
    vj0[k] = v1[(size_t)(b0 + 4*k)*32 + e];
    vj1[k] = v1[(size_t)(b0 + 4*k)*32 + 16 + e];
  }
  __syncthreads();

  float acc0[4] = {0,0,0,0}, acc1[4] = {0,0,0,0};
  #pragma unroll 1
  for (int ni=0; ni<NBT; ni+=2){
    ldx(xp, ni+1, xaB, xbB);
    body2(smem4, ni,   sA, sB, xaA, xbA, vj0, vj1, acc0, acc1);
    if (ni+2 < NBT) ldx(xp, ni+2, xaA, xbA);
    body2(smem4, ni+1, sA, sB, xaB, xbB, vj0, vj1, acc0, acc1);
  }

  float* dst = partial + (size_t)(blockIdx.x*4 + blockIdx.y)*2048
             + (wv*16 + blo)*32 + e;
  #pragma unroll
  for (int k=0;k<4;++k){ dst[k*128] = acc0[k]; dst[k*128+16] = acc1[k]; }
}

// Fused reduce (sum CGX chunk-partials, split-K by 2) + squash.
// grid 64 x 256: tid&127 -> output within block's 128, tid>>7 -> K-half.
template<bool HALF>
__global__ __launch_bounds__(256) void kred(const float* __restrict__ partial,
                                            float* __restrict__ dst)
{
  __shared__ float sh[128];
  const int tid  = threadIdx.x;
  const int o    = blockIdx.x*128 + (tid & 127);   // 64*128 = 8192 outputs
  const int half = tid >> 7;
  const int btile = o >> 11, q = o & 2047;
  const float* p = partial + (size_t)btile*2048 + q + (size_t)half*(CGX/2)*8192;
  float s = 0.f;
  #pragma unroll 24
  for (int cx=0; cx<CGX/2; ++cx) s += p[(size_t)cx*8192];
  if (half) sh[tid & 127] = s;
  __syncthreads();
  if (!half){
    s += sh[tid & 127];
    if (HALF) s *= 0.5f;
    float n2 = s*s;
    #pragma unroll
    for (int m=1; m<16; m<<=1) n2 += __shfl_xor(n2, m);
    dst[o] = s * (n2/(1.f+n2)) * rsqrtf(n2 + 1e-9f);
  }
}

// ---------------- fallback: monolithic (no ws) ----------------
#define NT 512
__global__ __launch_bounds__(NT) void kmono(const float* __restrict__ x,
                                            const float* __restrict__ W,
                                            float* __restrict__ out)
{
  const int b    = blockIdx.x;
  const int tid  = threadIdx.x;
  const int wv   = tid >> 6;
  const int lane = tid & 63;
  __shared__ float wred[8*33];
  __shared__ float vsh[32];

  float acc[32];
  #pragma unroll
  for (int i=0;i<32;++i) acc[i]=0.f;
  for (int n = tid; n < N_; n += NT){
    const float4 xa = *(const float4*)(x + ((size_t)b*N_ + n)*D_);
    const float4 xb = *(const float4*)(x + ((size_t)b*N_ + n)*D_ + 4);
    #pragma unroll
    for (int j=0;j<J_;++j){
      const float* wp = W + ((size_t)j*N_ + n)*(E_*D_);
      #pragma unroll
      for (int e=0;e<E_;++e){
        const float4 wa = *(const float4*)(wp + e*8);
        const float4 wb = *(const float4*)(wp + e*8 + 4);
        float a = acc[j*16+e];
        a = fmaf(wa.x,xa.x,a); a = fmaf(wa.y,xa.y,a); a = fmaf(wa.z,xa.z,a); a = fmaf(wa.w,xa.w,a);
        a = fmaf(wb.x,xb.x,a); a = fmaf(wb.y,xb.y,a); a = fmaf(wb.z,xb.z,a); a = fmaf(wb.w,xb.w,a);
        acc[j*16+e] = a;
      }
    }
  }
  #pragma unroll
  for (int i=0;i<32;++i){
    float v = acc[i];
    #pragma unroll
    for (int off=32; off; off>>=1) v += __shfl_xor(v, off);
    acc[i] = v;
  }
  if (lane == 0){
    #pragma unroll
    for (int i=0;i<32;++i) wred[wv*33 + i] = acc[i];
  }
  __syncthreads();
  if (tid < 32){
    float s = 0.f;
    #pragma unroll
    for (int w=0;w<8;++w) s += wred[w*33 + tid];
    wred[tid] = 0.5f * s;
  }
  __syncthreads();
  if (tid < 32){
    const int j = tid >> 4; float n2 = 0.f;
    #pragma unroll
    for (int e=0;e<16;++e){ const float sv = wred[j*16+e]; n2 = fmaf(sv,sv,n2); }
    vsh[tid] = wred[tid] * (n2/(1.f+n2)) * rsqrtf(n2 + 1e-9f);
  }
  __syncthreads();
  float vv[32];
  #pragma unroll
  for (int i=0;i<32;++i) vv[i] = vsh[i];

  #pragma unroll
  for (int i=0;i<32;++i) acc[i]=0.f;
  for (int n = tid; n < N_; n += NT){
    const float4 xa = *(const float4*)(x + ((size_t)b*N_ + n)*D_);
    const float4 xb = *(const float4*)(x + ((size_t)b*N_ + n)*D_ + 4);
    float u[32];
    #pragma unroll
    for (int j=0;j<J_;++j){
      const float* wp = W + ((size_t)j*N_ + n)*(E_*D_);
      #pragma unroll
      for (int e=0;e<E_;++e){
        const float4 wa = *(const float4*)(wp + e*8);
        const float4 wb = *(const float4*)(wp + e*8 + 4);
        float a;
        a = wa.x*xa.x; a = fmaf(wa.y,xa.y,a); a = fmaf(wa.z,xa.z,a); a = fmaf(wa.w,xa.w,a);
        a = fmaf(wb.x,xb.x,a); a = fmaf(wb.y,xb.y,a); a = fmaf(wb.z,xb.z,a); a = fmaf(wb.w,xb.w,a);
        u[j*16+e] = a;
      }
    }
    float l0=0.f, l1=0.f;
    #pragma unroll
    for (int e=0;e<16;++e){ l0 = fmaf(vv[e],u[e],l0); l1 = fmaf(vv[16+e],u[16+e],l1); }
    const float c0 = 1.f/(1.f + __expf(l1 - l0));
    const float c1 = 1.f - c0;
    #pragma unroll
    for (int e=0;e<16;++e){ acc[e] = fmaf(c0,u[e],acc[e]); acc[16+e] = fmaf(c1,u[16+e],acc[16+e]); }
  }
  #pragma unroll
  for (int i=0;i<32;++i){
    float v = acc[i];
    #pragma unroll
    for (int off=32; off; off>>=1) v += __shfl_xor(v, off);
    acc[i] = v;
  }
  __syncthreads();
  if (lane == 0){
    #pragma unroll
    for (int i=0;i<32;++i) wred[wv*33 + i] = acc[i];
  }
  __syncthreads();
  if (tid < 32){
    float s = 0.f;
    #pragma unroll
    for (int w=0;w<8;++w) s += wred[w*33 + tid];
    wred[tid] = s;
  }
  __syncthreads();
  if (tid < 32){
    const int j = tid >> 4; float n2 = 0.f;
    #pragma unroll
    for (int e=0;e<16;++e){ const float sv = wred[j*16+e]; n2 = fmaf(sv,sv,n2); }
    out[(size_t)b*32 + tid] = wred[tid] * (n2/(1.f+n2)) * rsqrtf(n2 + 1e-9f);
  }
}

extern "C" void kernel_launch(void* const* d_in, const int* in_sizes, int n_in,
                              void* d_out, int out_size, void* d_ws, size_t ws_size,
                              hipStream_t stream)
{
  const float* x = (const float*)d_in[0];   // [256,6912,8]
  const float* W = (const float*)d_in[1];   // [2,6912,16,8]
  if (n_in >= 2 && in_sizes[0] < in_sizes[1]){
    x = (const float*)d_in[1]; W = (const float*)d_in[0];
  }
  float* out = (float*)d_out;               // fp32 [256,2,16]

  const size_t need = (size_t)(8192 + (size_t)CGX*4*2048) * sizeof(float);  // ~12.6 MB

  if (ws_size >= need){
    float* wsf     = (float*)d_ws;
    float* v1      = wsf;           // 8192 floats
    float* partial = wsf + 8192;    // CGX*4*2048 floats
    kpass1<<<dim3(CGX,4), 256, 0, stream>>>(x, W, partial);
    kred<true ><<<64, 256, 0, stream>>>(partial, v1);
    kpass2<<<dim3(CGX,4), 256, 0, stream>>>(x, W, v1, partial);
    kred<false><<<64, 256, 0, stream>>>(partial, out);
  } else {
    kmono<<<B_, NT, 0, stream>>>(x, W, out);
  }
}

// Round 5
// 172.294 us; speedup vs baseline: 3.6047x; 3.6047x over previous
//
#include <hip/hip_runtime.h>

// Capsule routing: B=256, J=2, N=6912, E=16, D=8, 2 routing iters. All fp32.
// R15: R14 post-mortem: __launch_bounds__(256,6) forced VGPR 48->40 and spilled
// the x-prefetch ping-pong to scratch (WRITE_SIZE 1.05GB, kpass 403us @ VALU 4%).
// Revert to (256,4) (R12-proven 48 VGPR, no spill) and let RUNTIME occupancy
// float: NBT=18 -> 18.4KB LDS (8 blocks/CU LDS-cap), VGPR<=64 -> 8 waves/SIMD
// cap, grid 1536 = 6 blocks/CU fully co-resident. 6 waves/SIMD x ~170cyc/iter
// issue ~= 1000cyc >= ~900cyc HBM latency (R12's 4 waves were short).
// kred split-K by 2 (64 blocks). Spill tripwires: WRITE_SIZE ~13MB/pass, VGPR 48-64.
#define B_ 256
#define J_ 2
#define N_ 6912
#define E_ 16
#define D_ 8
#define NBT 18                 // n per block tile (even)
#define CGX 384                // grid (CGX,4) = 1536 blocks = 6/CU resident
#define TOT4 (J_*NBT*32)       // float4 units in W tile = 1152 (18432 B)
#define BSTR (4*N_*D_)         // float stride between a thread's consecutive b's

// sum over the 16-lane row (e-lanes sharing b_lo), pure VALU/DPP:
__device__ __forceinline__ float dpp_row_add16(float v){
  v += __int_as_float(__builtin_amdgcn_update_dpp(0, __float_as_int(v), 0xB1,  0xF, 0xF, true)); // xor 1
  v += __int_as_float(__builtin_amdgcn_update_dpp(0, __float_as_int(v), 0x4E,  0xF, 0xF, true)); // xor 2
  v += __int_as_float(__builtin_amdgcn_update_dpp(0, __float_as_int(v), 0x141, 0xF, 0xF, true)); // xor 7
  v += __int_as_float(__builtin_amdgcn_update_dpp(0, __float_as_int(v), 0x140, 0xF, 0xF, true)); // xor 15
  return v;
}

__device__ __forceinline__ void ldx(const float* __restrict__ xp, int ni,
                                    float4 (&xa)[4], float4 (&xb)[4]){
  #pragma unroll
  for (int k=0;k<4;++k){
    xa[k] = *(const float4*)(xp + (size_t)k*BSTR + ni*8);
    xb[k] = *(const float4*)(xp + (size_t)k*BSTR + ni*8 + 4);
  }
}

__device__ __forceinline__ void body1(const float4* __restrict__ smem4, int ni,
                                      int sA, int sB,
                                      const float4 (&xa)[4], const float4 (&xb)[4],
                                      float (&acc0)[4], float (&acc1)[4]){
  const float4 wa0 = smem4[ni*32 + sA];
  const float4 wb0 = smem4[ni*32 + sB];
  const float4 wa1 = smem4[(NBT + ni)*32 + sA];
  const float4 wb1 = smem4[(NBT + ni)*32 + sB];
  #pragma unroll
  for (int k=0;k<4;++k){
    float a0 = acc0[k], a1 = acc1[k];
    a0 = fmaf(wa0.x, xa[k].x, a0); a0 = fmaf(wa0.y, xa[k].y, a0);
    a0 = fmaf(wa0.z, xa[k].z, a0); a0 = fmaf(wa0.w, xa[k].w, a0);
    a0 = fmaf(wb0.x, xb[k].x, a0); a0 = fmaf(wb0.y, xb[k].y, a0);
    a0 = fmaf(wb0.z, xb[k].z, a0); a0 = fmaf(wb0.w, xb[k].w, a0);
    a1 = fmaf(wa1.x, xa[k].x, a1); a1 = fmaf(wa1.y, xa[k].y, a1);
    a1 = fmaf(wa1.z, xa[k].z, a1); a1 = fmaf(wa1.w, xa[k].w, a1);
    a1 = fmaf(wb1.x, xb[k].x, a1); a1 = fmaf(wb1.y, xb[k].y, a1);
    a1 = fmaf(wb1.z, xb[k].z, a1); a1 = fmaf(wb1.w, xb[k].w, a1);
    acc0[k] = a0; acc1[k] = a1;
  }
}

__device__ __forceinline__ void body2(const float4* __restrict__ smem4, int ni,
                                      int sA, int sB,
                                      const float4 (&xa)[4], const float4 (&xb)[4],
                                      const float (&vj0)[4], const float (&vj1)[4],
                                      float (&acc0)[4], float (&acc1)[4]){
  const float4 wa0 = smem4[ni*32 + sA];
  const float4 wb0 = smem4[ni*32 + sB];
  const float4 wa1 = smem4[(NBT + ni)*32 + sA];
  const float4 wb1 = smem4[(NBT + ni)*32 + sB];
  float u0[4], u1[4];
  #pragma unroll
  for (int k=0;k<4;++k){
    float a0, a1;
    a0 = wa0.x*xa[k].x;            a0 = fmaf(wa0.y, xa[k].y, a0);
    a0 = fmaf(wa0.z, xa[k].z, a0); a0 = fmaf(wa0.w, xa[k].w, a0);
    a0 = fmaf(wb0.x, xb[k].x, a0); a0 = fmaf(wb0.y, xb[k].y, a0);
    a0 = fmaf(wb0.z, xb[k].z, a0); a0 = fmaf(wb0.w, xb[k].w, a0);
    a1 = wa1.x*xa[k].x;            a1 = fmaf(wa1.y, xa[k].y, a1);
    a1 = fmaf(wa1.z, xa[k].z, a1); a1 = fmaf(wa1.w, xa[k].w, a1);
    a1 = fmaf(wb1.x, xb[k].x, a1); a1 = fmaf(wb1.y, xb[k].y, a1);
    a1 = fmaf(wb1.z, xb[k].z, a1); a1 = fmaf(wb1.w, xb[k].w, a1);
    u0[k] = a0; u1[k] = a1;
  }
  #pragma unroll
  for (int k=0;k<4;++k){
    const float d  = dpp_row_add16(fmaf(vj1[k], u1[k], -(vj0[k]*u0[k])));
    const float c0 = __builtin_amdgcn_rcpf(1.f + __expf(d));   // softmax over 2 caps
    acc0[k] = fmaf(c0,       u0[k], acc0[k]);
    acc1[k] = fmaf(1.f - c0, u1[k], acc1[k]);
  }
}

// Stage W[j][NBT n][16 e][8 d] -> LDS, XOR-swizzled in 16B units within each
// 32-unit row. 3+2 register rounds (<=12 float4 live; R12's single batch spilled).
__device__ __forceinline__ void stageW(const float* __restrict__ W, int nb0, int tid,
                                       float* __restrict__ smem){
  {
    float4 buf[3];
    #pragma unroll
    for (int k=0;k<3;++k){
      const int idx = k*256 + tid;
      const int j  = (idx >= NBT*32) ? 1 : 0;
      const int r4 = idx - j*(NBT*32);
      buf[k] = *(const float4*)(W + ((size_t)j*N_ + nb0)*(E_*D_) + (size_t)r4*4);
    }
    #pragma unroll
    for (int k=0;k<3;++k){
      const int idx = k*256 + tid;
      const int u = idx & 31;
      *(float4*)(smem + (size_t)((idx & ~31) | (u ^ (u>>3)))*4) = buf[k];
    }
  }
  {
    float4 buf[2];
    #pragma unroll
    for (int k=0;k<2;++k){
      const int idx = (k+3)*256 + tid;
      if (idx < TOT4){
        const int j  = (idx >= NBT*32) ? 1 : 0;
        const int r4 = idx - j*(NBT*32);
        buf[k] = *(const float4*)(W + ((size_t)j*N_ + nb0)*(E_*D_) + (size_t)r4*4);
      }
    }
    #pragma unroll
    for (int k=0;k<2;++k){
      const int idx = (k+3)*256 + tid;
      if (idx < TOT4){
        const int u = idx & 31;
        *(float4*)(smem + (size_t)((idx & ~31) | (u ^ (u>>3)))*4) = buf[k];
      }
    }
  }
}

// ---------------- main path (4 launches) ----------------

__global__ __launch_bounds__(256, 4) void kpass1(const float* __restrict__ x,
                                                 const float* __restrict__ W,
                                                 float* __restrict__ partial)
{
  __shared__ float smem[TOT4*4];   // 18432 B
  const int tid  = threadIdx.x;
  const int lane = tid & 63;
  const int wv   = __builtin_amdgcn_readfirstlane(tid >> 6);
  const int e    = lane & 15;
  const int blo  = lane >> 4;
  const int nb0  = blockIdx.x * NBT;
  const int b0   = blockIdx.y*64 + wv*16 + blo;
  const float* xp = x + ((size_t)b0*N_ + nb0)*D_;
  const int sA = (e*2)   ^ ((e*2)>>3);
  const int sB = (e*2+1) ^ ((e*2+1)>>3);
  const float4* smem4 = (const float4*)smem;

  stageW(W, nb0, tid, smem);
  float4 xaA[4], xbA[4], xaB[4], xbB[4];
  ldx(xp, 0, xaA, xbA);
  __syncthreads();

  float acc0[4] = {0,0,0,0}, acc1[4] = {0,0,0,0};
  #pragma unroll 1
  for (int ni=0; ni<NBT; ni+=2){
    ldx(xp, ni+1, xaB, xbB);
    body1(smem4, ni,   sA, sB, xaA, xbA, acc0, acc1);
    if (ni+2 < NBT) ldx(xp, ni+2, xaA, xbA);
    body1(smem4, ni+1, sA, sB, xaB, xbB, acc0, acc1);
  }

  float* dst = partial + (size_t)(blockIdx.x*4 + blockIdx.y)*2048
             + (wv*16 + blo)*32 + e;
  #pragma unroll
  for (int k=0;k<4;++k){ dst[k*128] = acc0[k]; dst[k*128+16] = acc1[k]; }
}

__global__ __launch_bounds__(256, 4) void kpass2(const float* __restrict__ x,
                                                 const float* __restrict__ W,
                                                 const float* __restrict__ v1,
                                                 float* __restrict__ partial)
{
  __shared__ float smem[TOT4*4];
  const int tid  = threadIdx.x;
  const int lane = tid & 63;
  const int wv   = __builtin_amdgcn_readfirstlane(tid >> 6);
  const int e    = lane & 15;
  const int blo  = lane >> 4;
  const int nb0  = blockIdx.x * NBT;
  const int b0   = blockIdx.y*64 + wv*16 + blo;
  const float* xp = x + ((size_t)b0*N_ + nb0)*D_;
  const int sA = (e*2)   ^ ((e*2)>>3);
  const int sB = (e*2+1) ^ ((e*2+1)>>3);
  const float4* smem4 = (const float4*)smem;

  stageW(W, nb0, tid, smem);
  float4 xaA[4], xbA[4], xaB[4], xbB[4];
  ldx(xp, 0, xaA, xbA);
  float vj0[4], vj1[4];
  #pragma unroll
  for (int k=0;k<4;++k){
    vj0[k] = v1[(size_t)(b0 + 4*k)*32 + e];
    vj1[k] = v1[(size_t)(b0 + 4*k)*32 + 16 + e];
  }
  __syncthreads();

  float acc0[4] = {0,0,0,0}, acc1[4] = {0,0,0,0};
  #pragma unroll 1
  for (int ni=0; ni<NBT; ni+=2){
    ldx(xp, ni+1, xaB, xbB);
    body2(smem4, ni,   sA, sB, xaA, xbA, vj0, vj1, acc0, acc1);
    if (ni+2 < NBT) ldx(xp, ni+2, xaA, xbA);
    body2(smem4, ni+1, sA, sB, xaB, xbB, vj0, vj1, acc0, acc1);
  }

  float* dst = partial + (size_t)(blockIdx.x*4 + blockIdx.y)*2048
             + (wv*16 + blo)*32 + e;
  #pragma unroll
  for (int k=0;k<4;++k){ dst[k*128] = acc0[k]; dst[k*128+16] = acc1[k]; }
}

// Fused reduce (sum CGX chunk-partials, split-K by 2) + squash.
// grid 64 x 256: tid&127 -> output within block's 128, tid>>7 -> K-half.
template<bool HALF>
__global__ __launch_bounds__(256) void kred(const float* __restrict__ partial,
                                            float* __restrict__ dst)
{
  __shared__ float sh[128];
  const int tid  = threadIdx.x;
  const int o    = blockIdx.x*128 + (tid & 127);   // 64*128 = 8192 outputs
  const int half = tid >> 7;
  const int btile = o >> 11, q = o & 2047;
  const float* p = partial + (size_t)btile*2048 + q + (size_t)half*(CGX/2)*8192;
  float s = 0.f;
  #pragma unroll 24
  for (int cx=0; cx<CGX/2; ++cx) s += p[(size_t)cx*8192];
  if (half) sh[tid & 127] = s;
  __syncthreads();
  if (!half){
    s += sh[tid & 127];
    if (HALF) s *= 0.5f;
    float n2 = s*s;
    #pragma unroll
    for (int m=1; m<16; m<<=1) n2 += __shfl_xor(n2, m);
    dst[o] = s * (n2/(1.f+n2)) * rsqrtf(n2 + 1e-9f);
  }
}

// ---------------- fallback: monolithic (no ws) ----------------
#define NT 512
__global__ __launch_bounds__(NT) void kmono(const float* __restrict__ x,
                                            const float* __restrict__ W,
                                            float* __restrict__ out)
{
  const int b    = blockIdx.x;
  const int tid  = threadIdx.x;
  const int wv   = tid >> 6;
  const int lane = tid & 63;
  __shared__ float wred[8*33];
  __shared__ float vsh[32];

  float acc[32];
  #pragma unroll
  for (int i=0;i<32;++i) acc[i]=0.f;
  for (int n = tid; n < N_; n += NT){
    const float4 xa = *(const float4*)(x + ((size_t)b*N_ + n)*D_);
    const float4 xb = *(const float4*)(x + ((size_t)b*N_ + n)*D_ + 4);
    #pragma unroll
    for (int j=0;j<J_;++j){
      const float* wp = W + ((size_t)j*N_ + n)*(E_*D_);
      #pragma unroll
      for (int e=0;e<E_;++e){
        const float4 wa = *(const float4*)(wp + e*8);
        const float4 wb = *(const float4*)(wp + e*8 + 4);
        float a = acc[j*16+e];
        a = fmaf(wa.x,xa.x,a); a = fmaf(wa.y,xa.y,a); a = fmaf(wa.z,xa.z,a); a = fmaf(wa.w,xa.w,a);
        a = fmaf(wb.x,xb.x,a); a = fmaf(wb.y,xb.y,a); a = fmaf(wb.z,xb.z,a); a = fmaf(wb.w,xb.w,a);
        acc[j*16+e] = a;
      }
    }
  }
  #pragma unroll
  for (int i=0;i<32;++i){
    float v = acc[i];
    #pragma unroll
    for (int off=32; off; off>>=1) v += __shfl_xor(v, off);
    acc[i] = v;
  }
  if (lane == 0){
    #pragma unroll
    for (int i=0;i<32;++i) wred[wv*33 + i] = acc[i];
  }
  __syncthreads();
  if (tid < 32){
    float s = 0.f;
    #pragma unroll
    for (int w=0;w<8;++w) s += wred[w*33 + tid];
    wred[tid] = 0.5f * s;
  }
  __syncthreads();
  if (tid < 32){
    const int j = tid >> 4; float n2 = 0.f;
    #pragma unroll
    for (int e=0;e<16;++e){ const float sv = wred[j*16+e]; n2 = fmaf(sv,sv,n2); }
    vsh[tid] = wred[tid] * (n2/(1.f+n2)) * rsqrtf(n2 + 1e-9f);
  }
  __syncthreads();
  float vv[32];
  #pragma unroll
  for (int i=0;i<32;++i) vv[i] = vsh[i];

  #pragma unroll
  for (int i=0;i<32;++i) acc[i]=0.f;
  for (int n = tid; n < N_; n += NT){
    const float4 xa = *(const float4*)(x + ((size_t)b*N_ + n)*D_);
    const float4 xb = *(const float4*)(x + ((size_t)b*N_ + n)*D_ + 4);
    float u[32];
    #pragma unroll
    for (int j=0;j<J_;++j){
      const float* wp = W + ((size_t)j*N_ + n)*(E_*D_);
      #pragma unroll
      for (int e=0;e<E_;++e){
        const float4 wa = *(const float4*)(wp + e*8);
        const float4 wb = *(const float4*)(wp + e*8 + 4);
        float a;
        a = wa.x*xa.x; a = fmaf(wa.y,xa.y,a); a = fmaf(wa.z,xa.z,a); a = fmaf(wa.w,xa.w,a);
        a = fmaf(wb.x,xb.x,a); a = fmaf(wb.y,xb.y,a); a = fmaf(wb.z,xb.z,a); a = fmaf(wb.w,xb.w,a);
        u[j*16+e] = a;
      }
    }
    float l0=0.f, l1=0.f;
    #pragma unroll
    for (int e=0;e<16;++e){ l0 = fmaf(vv[e],u[e],l0); l1 = fmaf(vv[16+e],u[16+e],l1); }
    const float c0 = 1.f/(1.f + __expf(l1 - l0));
    const float c1 = 1.f - c0;
    #pragma unroll
    for (int e=0;e<16;++e){ acc[e] = fmaf(c0,u[e],acc[e]); acc[16+e] = fmaf(c1,u[16+e],acc[16+e]); }
  }
  #pragma unroll
  for (int i=0;i<32;++i){
    float v = acc[i];
    #pragma unroll
    for (int off=32; off; off>>=1) v += __shfl_xor(v, off);
    acc[i] = v;
  }
  __syncthreads();
  if (lane == 0){
    #pragma unroll
    for (int i=0;i<32;++i) wred[wv*33 + i] = acc[i];
  }
  __syncthreads();
  if (tid < 32){
    float s = 0.f;
    #pragma unroll
    for (int w=0;w<8;++w) s += wred[w*33 + tid];
    wred[tid] = s;
  }
  __syncthreads();
  if (tid < 32){
    const int j = tid >> 4; float n2 = 0.f;
    #pragma unroll
    for (int e=0;e<16;++e){ const float sv = wred[j*16+e]; n2 = fmaf(sv,sv,n2); }
    out[(size_t)b*32 + tid] = wred[tid] * (n2/(1.f+n2)) * rsqrtf(n2 + 1e-9f);
  }
}

extern "C" void kernel_launch(void* const* d_in, const int* in_sizes, int n_in,
                              void* d_out, int out_size, void* d_ws, size_t ws_size,
                              hipStream_t stream)
{
  const float* x = (const float*)d_in[0];   // [256,6912,8]
  const float* W = (const float*)d_in[1];   // [2,6912,16,8]
  if (n_in >= 2 && in_sizes[0] < in_sizes[1]){
    x = (const float*)d_in[1]; W = (const float*)d_in[0];
  }
  float* out = (float*)d_out;               // fp32 [256,2,16]

  const size_t need = (size_t)(8192 + (size_t)CGX*4*2048) * sizeof(float);  // ~12.6 MB

  if (ws_size >= need){
    float* wsf     = (float*)d_ws;
    float* v1      = wsf;           // 8192 floats
    float* partial = wsf + 8192;    // CGX*4*2048 floats
    kpass1<<<dim3(CGX,4), 256, 0, stream>>>(x, W, partial);
    kred<true ><<<64, 256, 0, stream>>>(partial, v1);
    kpass2<<<dim3(CGX,4), 256, 0, stream>>>(x, W, v1, partial);
    kred<false><<<64, 256, 0, stream>>>(partial, out);
  } else {
    kmono<<<B_, NT, 0, stream>>>(x, W, out);
  }
}

// Round 6
// 153.021 us; speedup vs baseline: 4.0587x; 1.1260x over previous
//
#include <hip/hip_runtime.h>

// Capsule routing: B=256, J=2, N=6912, E=16, D=8, 2 routing iters. All fp32.
// R16: R15 showed per-iter global x loads can't be latency-hidden by occupancy
// (VALUBusy 30% at 6 blocks/CU; depth-1.5 prefetch vs 400-900cyc latency).
// Fix: stage x in LDS too (burst, 9 outstanding f4 loads/thread, once/block);
// inner loop is pure LDS+FMA: 12 ds_read_b128 + 64 FMA per n-iter, all LDS
// offsets fold to base+imm (zero address VALU). x LDS rows padded to 25 f4
// (100 floats): blo-stride banks {0,4,8,12} conflict-free; e-lanes broadcast.
// NBT=12/CGX=576: LDS 37.9KB -> 4 blocks/CU resident, 9 demanded (backlog).
// Spill tripwires: VGPR<=128, WRITE_SIZE ~20MB/pass.
#define B_ 256
#define J_ 2
#define N_ 6912
#define E_ 16
#define D_ 8
#define NBT 12                 // n per block tile
#define CGX 576                // grid (CGX,4) = 2304 blocks
#define TOT4 (J_*NBT*32)       // 768 f4 = 12.3 KB W tile
#define XROW 25                // f4 per b-row in x LDS (24 data + 1 pad)
#define XTOT4 (64*XROW)        // 1600 f4 = 25.6 KB x tile

// sum over the 16-lane row (e-lanes sharing b_lo), pure VALU/DPP:
__device__ __forceinline__ float dpp_row_add16(float v){
  v += __int_as_float(__builtin_amdgcn_update_dpp(0, __float_as_int(v), 0xB1,  0xF, 0xF, true)); // xor 1
  v += __int_as_float(__builtin_amdgcn_update_dpp(0, __float_as_int(v), 0x4E,  0xF, 0xF, true)); // xor 2
  v += __int_as_float(__builtin_amdgcn_update_dpp(0, __float_as_int(v), 0x141, 0xF, 0xF, true)); // xor 7
  v += __int_as_float(__builtin_amdgcn_update_dpp(0, __float_as_int(v), 0x140, 0xF, 0xF, true)); // xor 15
  return v;
}

// Stage W (swizzled) + x (padded rows) into LDS. All 9 global f4 loads issued
// before any LDS write (max MLP, <=40 live regs, no R12-style spill pattern).
__device__ __forceinline__ void stageWX(const float* __restrict__ W,
                                        const float* __restrict__ x,
                                        int nb0, int by64, int tid,
                                        float4* __restrict__ Wl,
                                        float4* __restrict__ Xl){
  float4 bw[3], bx[6];
  #pragma unroll
  for (int r=0;r<3;++r){
    const int idx = r*256 + tid;                 // 0..767
    const int j  = (idx >= NBT*32) ? 1 : 0;
    const int r4 = idx - j*(NBT*32);
    bw[r] = *(const float4*)(W + ((size_t)j*N_ + nb0)*(E_*D_) + (size_t)r4*4);
  }
  #pragma unroll
  for (int r=0;r<6;++r){
    const int g = r*256 + tid;                   // 0..1535
    const int brow = g/24, c = g - brow*24;      // 24 f4 per b-row (12n x 8d)
    bx[r] = *(const float4*)(x + ((size_t)(by64 + brow)*N_ + nb0)*D_ + c*4);
  }
  #pragma unroll
  for (int r=0;r<3;++r){
    const int idx = r*256 + tid;
    const int u = idx & 31;
    Wl[(idx & ~31) | (u ^ (u>>3))] = bw[r];
  }
  #pragma unroll
  for (int r=0;r<6;++r){
    const int g = r*256 + tid;
    const int brow = g/24, c = g - brow*24;
    Xl[brow*XROW + c] = bx[r];
  }
}

// ---------------- main path (4 launches) ----------------

__global__ __launch_bounds__(256, 4) void kpass1(const float* __restrict__ x,
                                                 const float* __restrict__ W,
                                                 float* __restrict__ partial)
{
  __shared__ float4 smem4[TOT4 + XTOT4];   // 37888 B
  float4* Wl = smem4;
  float4* Xl = smem4 + TOT4;
  const int tid  = threadIdx.x;
  const int lane = tid & 63;
  const int wv   = __builtin_amdgcn_readfirstlane(tid >> 6);
  const int e    = lane & 15;
  const int blo  = lane >> 4;
  const int nb0  = blockIdx.x * NBT;
  const int sA = (e*2)   ^ ((e*2)>>3);
  const int sB = (e*2+1) ^ ((e*2+1)>>3);

  stageWX(W, x, nb0, blockIdx.y*64, tid, Wl, Xl);
  __syncthreads();

  const float4* Xr = Xl + (wv*16 + blo)*XROW;    // thread's first b-row
  float acc0[4] = {0,0,0,0}, acc1[4] = {0,0,0,0};
  #pragma unroll 1
  for (int ni=0; ni<NBT; ++ni){
    const float4 wa0 = Wl[ni*32 + sA];
    const float4 wb0 = Wl[ni*32 + sB];
    const float4 wa1 = Wl[(NBT+ni)*32 + sA];
    const float4 wb1 = Wl[(NBT+ni)*32 + sB];
    #pragma unroll
    for (int k=0;k<4;++k){
      const float4 xa = Xr[k*(4*XROW) + ni*2];
      const float4 xb = Xr[k*(4*XROW) + ni*2 + 1];
      float a0 = acc0[k], a1 = acc1[k];
      a0 = fmaf(wa0.x, xa.x, a0); a0 = fmaf(wa0.y, xa.y, a0);
      a0 = fmaf(wa0.z, xa.z, a0); a0 = fmaf(wa0.w, xa.w, a0);
      a0 = fmaf(wb0.x, xb.x, a0); a0 = fmaf(wb0.y, xb.y, a0);
      a0 = fmaf(wb0.z, xb.z, a0); a0 = fmaf(wb0.w, xb.w, a0);
      a1 = fmaf(wa1.x, xa.x, a1); a1 = fmaf(wa1.y, xa.y, a1);
      a1 = fmaf(wa1.z, xa.z, a1); a1 = fmaf(wa1.w, xa.w, a1);
      a1 = fmaf(wb1.x, xb.x, a1); a1 = fmaf(wb1.y, xb.y, a1);
      a1 = fmaf(wb1.z, xb.z, a1); a1 = fmaf(wb1.w, xb.w, a1);
      acc0[k] = a0; acc1[k] = a1;
    }
  }

  float* dst = partial + (size_t)(blockIdx.x*4 + blockIdx.y)*2048
             + (wv*16 + blo)*32 + e;
  #pragma unroll
  for (int k=0;k<4;++k){ dst[k*128] = acc0[k]; dst[k*128+16] = acc1[k]; }
}

__global__ __launch_bounds__(256, 4) void kpass2(const float* __restrict__ x,
                                                 const float* __restrict__ W,
                                                 const float* __restrict__ v1,
                                                 float* __restrict__ partial)
{
  __shared__ float4 smem4[TOT4 + XTOT4];
  float4* Wl = smem4;
  float4* Xl = smem4 + TOT4;
  const int tid  = threadIdx.x;
  const int lane = tid & 63;
  const int wv   = __builtin_amdgcn_readfirstlane(tid >> 6);
  const int e    = lane & 15;
  const int blo  = lane >> 4;
  const int nb0  = blockIdx.x * NBT;
  const int b0   = blockIdx.y*64 + wv*16 + blo;
  const int sA = (e*2)   ^ ((e*2)>>3);
  const int sB = (e*2+1) ^ ((e*2+1)>>3);

  stageWX(W, x, nb0, blockIdx.y*64, tid, Wl, Xl);
  float vj0[4], vj1[4];
  #pragma unroll
  for (int k=0;k<4;++k){
    vj0[k] = v1[(size_t)(b0 + 4*k)*32 + e];
    vj1[k] = v1[(size_t)(b0 + 4*k)*32 + 16 + e];
  }
  __syncthreads();

  const float4* Xr = Xl + (wv*16 + blo)*XROW;
  float acc0[4] = {0,0,0,0}, acc1[4] = {0,0,0,0};
  #pragma unroll 1
  for (int ni=0; ni<NBT; ++ni){
    const float4 wa0 = Wl[ni*32 + sA];
    const float4 wb0 = Wl[ni*32 + sB];
    const float4 wa1 = Wl[(NBT+ni)*32 + sA];
    const float4 wb1 = Wl[(NBT+ni)*32 + sB];
    #pragma unroll
    for (int k=0;k<4;++k){
      const float4 xa = Xr[k*(4*XROW) + ni*2];
      const float4 xb = Xr[k*(4*XROW) + ni*2 + 1];
      float a0, a1;
      a0 = wa0.x*xa.x;          a0 = fmaf(wa0.y, xa.y, a0);
      a0 = fmaf(wa0.z, xa.z, a0); a0 = fmaf(wa0.w, xa.w, a0);
      a0 = fmaf(wb0.x, xb.x, a0); a0 = fmaf(wb0.y, xb.y, a0);
      a0 = fmaf(wb0.z, xb.z, a0); a0 = fmaf(wb0.w, xb.w, a0);
      a1 = wa1.x*xa.x;          a1 = fmaf(wa1.y, xa.y, a1);
      a1 = fmaf(wa1.z, xa.z, a1); a1 = fmaf(wa1.w, xa.w, a1);
      a1 = fmaf(wb1.x, xb.x, a1); a1 = fmaf(wb1.y, xb.y, a1);
      a1 = fmaf(wb1.z, xb.z, a1); a1 = fmaf(wb1.w, xb.w, a1);
      const float d  = dpp_row_add16(fmaf(vj1[k], a1, -(vj0[k]*a0)));
      const float c0 = __builtin_amdgcn_rcpf(1.f + __expf(d));   // softmax over 2 caps
      acc0[k] = fmaf(c0,       a0, acc0[k]);
      acc1[k] = fmaf(1.f - c0, a1, acc1[k]);
    }
  }

  float* dst = partial + (size_t)(blockIdx.x*4 + blockIdx.y)*2048
             + (wv*16 + blo)*32 + e;
  #pragma unroll
  for (int k=0;k<4;++k){ dst[k*128] = acc0[k]; dst[k*128+16] = acc1[k]; }
}

// Fused reduce (sum CGX chunk-partials, split-K by 2) + squash.
// grid 64 x 256: tid&127 -> output within block's 128, tid>>7 -> K-half.
template<bool HALF>
__global__ __launch_bounds__(256) void kred(const float* __restrict__ partial,
                                            float* __restrict__ dst)
{
  __shared__ float sh[128];
  const int tid  = threadIdx.x;
  const int o    = blockIdx.x*128 + (tid & 127);   // 64*128 = 8192 outputs
  const int half = tid >> 7;
  const int btile = o >> 11, q = o & 2047;
  const float* p = partial + (size_t)btile*2048 + q + (size_t)half*(CGX/2)*8192;
  float s = 0.f;
  #pragma unroll 24
  for (int cx=0; cx<CGX/2; ++cx) s += p[(size_t)cx*8192];
  if (half) sh[tid & 127] = s;
  __syncthreads();
  if (!half){
    s += sh[tid & 127];
    if (HALF) s *= 0.5f;
    float n2 = s*s;
    #pragma unroll
    for (int m=1; m<16; m<<=1) n2 += __shfl_xor(n2, m);
    dst[o] = s * (n2/(1.f+n2)) * rsqrtf(n2 + 1e-9f);
  }
}

// ---------------- fallback: monolithic (no ws) ----------------
#define NT 512
__global__ __launch_bounds__(NT) void kmono(const float* __restrict__ x,
                                            const float* __restrict__ W,
                                            float* __restrict__ out)
{
  const int b    = blockIdx.x;
  const int tid  = threadIdx.x;
  const int wv   = tid >> 6;
  const int lane = tid & 63;
  __shared__ float wred[8*33];
  __shared__ float vsh[32];

  float acc[32];
  #pragma unroll
  for (int i=0;i<32;++i) acc[i]=0.f;
  for (int n = tid; n < N_; n += NT){
    const float4 xa = *(const float4*)(x + ((size_t)b*N_ + n)*D_);
    const float4 xb = *(const float4*)(x + ((size_t)b*N_ + n)*D_ + 4);
    #pragma unroll
    for (int j=0;j<J_;++j){
      const float* wp = W + ((size_t)j*N_ + n)*(E_*D_);
      #pragma unroll
      for (int e=0;e<E_;++e){
        const float4 wa = *(const float4*)(wp + e*8);
        const float4 wb = *(const float4*)(wp + e*8 + 4);
        float a = acc[j*16+e];
        a = fmaf(wa.x,xa.x,a); a = fmaf(wa.y,xa.y,a); a = fmaf(wa.z,xa.z,a); a = fmaf(wa.w,xa.w,a);
        a = fmaf(wb.x,xb.x,a); a = fmaf(wb.y,xb.y,a); a = fmaf(wb.z,xb.z,a); a = fmaf(wb.w,xb.w,a);
        acc[j*16+e] = a;
      }
    }
  }
  #pragma unroll
  for (int i=0;i<32;++i){
    float v = acc[i];
    #pragma unroll
    for (int off=32; off; off>>=1) v += __shfl_xor(v, off);
    acc[i] = v;
  }
  if (lane == 0){
    #pragma unroll
    for (int i=0;i<32;++i) wred[wv*33 + i] = acc[i];
  }
  __syncthreads();
  if (tid < 32){
    float s = 0.f;
    #pragma unroll
    for (int w=0;w<8;++w) s += wred[w*33 + tid];
    wred[tid] = 0.5f * s;
  }
  __syncthreads();
  if (tid < 32){
    const int j = tid >> 4; float n2 = 0.f;
    #pragma unroll
    for (int e=0;e<16;++e){ const float sv = wred[j*16+e]; n2 = fmaf(sv,sv,n2); }
    vsh[tid] = wred[tid] * (n2/(1.f+n2)) * rsqrtf(n2 + 1e-9f);
  }
  __syncthreads();
  float vv[32];
  #pragma unroll
  for (int i=0;i<32;++i) vv[i] = vsh[i];

  #pragma unroll
  for (int i=0;i<32;++i) acc[i]=0.f;
  for (int n = tid; n < N_; n += NT){
    const float4 xa = *(const float4*)(x + ((size_t)b*N_ + n)*D_);
    const float4 xb = *(const float4*)(x + ((size_t)b*N_ + n)*D_ + 4);
    float u[32];
    #pragma unroll
    for (int j=0;j<J_;++j){
      const float* wp = W + ((size_t)j*N_ + n)*(E_*D_);
      #pragma unroll
      for (int e=0;e<E_;++e){
        const float4 wa = *(const float4*)(wp + e*8);
        const float4 wb = *(const float4*)(wp + e*8 + 4);
        float a;
        a = wa.x*xa.x; a = fmaf(wa.y,xa.y,a); a = fmaf(wa.z,xa.z,a); a = fmaf(wa.w,xa.w,a);
        a = fmaf(wb.x,xb.x,a); a = fmaf(wb.y,xb.y,a); a = fmaf(wb.z,xb.z,a); a = fmaf(wb.w,xb.w,a);
        u[j*16+e] = a;
      }
    }
    float l0=0.f, l1=0.f;
    #pragma unroll
    for (int e=0;e<16;++e){ l0 = fmaf(vv[e],u[e],l0); l1 = fmaf(vv[16+e],u[16+e],l1); }
    const float c0 = 1.f/(1.f + __expf(l1 - l0));
    const float c1 = 1.f - c0;
    #pragma unroll
    for (int e=0;e<16;++e){ acc[e] = fmaf(c0,u[e],acc[e]); acc[16+e] = fmaf(c1,u[16+e],acc[16+e]); }
  }
  #pragma unroll
  for (int i=0;i<32;++i){
    float v = acc[i];
    #pragma unroll
    for (int off=32; off; off>>=1) v += __shfl_xor(v, off);
    acc[i] = v;
  }
  __syncthreads();
  if (lane == 0){
    #pragma unroll
    for (int i=0;i<32;++i) wred[wv*33 + i] = acc[i];
  }
  __syncthreads();
  if (tid < 32){
    float s = 0.f;
    #pragma unroll
    for (int w=0;w<8;++w) s += wred[w*33 + tid];
    wred[tid] = s;
  }
  __syncthreads();
  if (tid < 32){
    const int j = tid >> 4; float n2 = 0.f;
    #pragma unroll
    for (int e=0;e<16;++e){ const float sv = wred[j*16+e]; n2 = fmaf(sv,sv,n2); }
    out[(size_t)b*32 + tid] = wred[tid] * (n2/(1.f+n2)) * rsqrtf(n2 + 1e-9f);
  }
}

extern "C" void kernel_launch(void* const* d_in, const int* in_sizes, int n_in,
                              void* d_out, int out_size, void* d_ws, size_t ws_size,
                              hipStream_t stream)
{
  const float* x = (const float*)d_in[0];   // [256,6912,8]
  const float* W = (const float*)d_in[1];   // [2,6912,16,8]
  if (n_in >= 2 && in_sizes[0] < in_sizes[1]){
    x = (const float*)d_in[1]; W = (const float*)d_in[0];
  }
  float* out = (float*)d_out;               // fp32 [256,2,16]

  const size_t need = (size_t)(8192 + (size_t)CGX*4*2048) * sizeof(float);  // ~18.9 MB

  if (ws_size >= need){
    float* wsf     = (float*)d_ws;
    float* v1      = wsf;           // 8192 floats
    float* partial = wsf + 8192;    // CGX*4*2048 floats
    kpass1<<<dim3(CGX,4), 256, 0, stream>>>(x, W, partial);
    kred<true ><<<64, 256, 0, stream>>>(partial, v1);
    kpass2<<<dim3(CGX,4), 256, 0, stream>>>(x, W, v1, partial);
    kred<false><<<64, 256, 0, stream>>>(partial, out);
  } else {
    kmono<<<B_, NT, 0, stream>>>(x, W, out);
  }
}

// Round 7
// 141.334 us; speedup vs baseline: 4.3943x; 1.0827x over previous
//
#include <hip/hip_runtime.h>

// Capsule routing: B=256, J=2, N=6912, E=16, D=8, 2 routing iters. All fp32.
// R17: R16 (153us, best) made the inner loop pure LDS+FMA; now LDS-issue-bound:
// 12 ds_read_b128 per 64 FMA (rho=0.1875), ~26us/pass on the CU-shared LDS pipe
// vs 5.8us VALU floor. Fix: e-pair lane map. lane=(bs:8 x eh:8); thread owns
// e in {eh, eh+8}, 4 b's (8k+bs), both j -> 16 b128 per 128 FMA (rho=0.125,
// balanced-operand optimum for a 32-b wave). Waves split {b-half} x {n-parity};
// 2-way n-parity merge via small LDS epilogue (16 b32 w + 16 r, 2 barriers).
// Pass2 logit e-sum now 3 DPP steps (xor1,xor2,half_mirror) over 8 eh-lanes.
// FMA/thread unchanged (768) -> VALU floor same; LDS instr 144 -> ~100.
// Tripwires: WRITE_SIZE ~22MB/pass (spill!), VGPR kpass1 ~100 / kpass2 ~125.
#define B_ 256
#define J_ 2
#define N_ 6912
#define E_ 16
#define D_ 8
#define NBT 12                 // n per block tile
#define CGX 576                // grid (CGX,4) = 2304 blocks
#define TOT4 (J_*NBT*32)       // 768 f4 = 12.3 KB W tile
#define XROW 25                // f4 per b-row in x LDS (24 data + 1 pad)
#define XTOT4 (64*XROW)        // 1600 f4 = 25.6 KB x tile

// sum over the 8 eh-lanes (lane low-3 bits), pure VALU/DPP:
__device__ __forceinline__ float dpp_add8(float v){
  v += __int_as_float(__builtin_amdgcn_update_dpp(0, __float_as_int(v), 0xB1,  0xF, 0xF, true)); // quad_perm xor1
  v += __int_as_float(__builtin_amdgcn_update_dpp(0, __float_as_int(v), 0x4E,  0xF, 0xF, true)); // quad_perm xor2
  v += __int_as_float(__builtin_amdgcn_update_dpp(0, __float_as_int(v), 0x141, 0xF, 0xF, true)); // row_half_mirror xor7
  return v;
}

__device__ __forceinline__ float dot8(const float4 wa, const float4 wb,
                                      const float4 xa, const float4 xb, float a){
  a = fmaf(wa.x, xa.x, a); a = fmaf(wa.y, xa.y, a);
  a = fmaf(wa.z, xa.z, a); a = fmaf(wa.w, xa.w, a);
  a = fmaf(wb.x, xb.x, a); a = fmaf(wb.y, xb.y, a);
  a = fmaf(wb.z, xb.z, a); a = fmaf(wb.w, xb.w, a);
  return a;
}

// Stage W (swizzled) + x (padded rows) into LDS. All 9 global f4 loads issued
// before any LDS write (max MLP; proven no-spill pattern from R16).
__device__ __forceinline__ void stageWX(const float* __restrict__ W,
                                        const float* __restrict__ x,
                                        int nb0, int by64, int tid,
                                        float4* __restrict__ Wl,
                                        float4* __restrict__ Xl){
  float4 bw[3], bx[6];
  #pragma unroll
  for (int r=0;r<3;++r){
    const int idx = r*256 + tid;                 // 0..767
    const int j  = (idx >= NBT*32) ? 1 : 0;
    const int r4 = idx - j*(NBT*32);
    bw[r] = *(const float4*)(W + ((size_t)j*N_ + nb0)*(E_*D_) + (size_t)r4*4);
  }
  #pragma unroll
  for (int r=0;r<6;++r){
    const int g = r*256 + tid;                   // 0..1535
    const int brow = g/24, c = g - brow*24;      // 24 f4 per b-row (12n x 8d)
    bx[r] = *(const float4*)(x + ((size_t)(by64 + brow)*N_ + nb0)*D_ + c*4);
  }
  #pragma unroll
  for (int r=0;r<3;++r){
    const int idx = r*256 + tid;
    const int u = idx & 31;
    Wl[(idx & ~31) | (u ^ (u>>3))] = bw[r];
  }
  #pragma unroll
  for (int r=0;r<6;++r){
    const int g = r*256 + tid;
    const int brow = g/24, c = g - brow*24;
    Xl[brow*XROW + c] = bx[r];
  }
}

// ---------------- main path (4 launches) ----------------

__global__ __launch_bounds__(256, 4) void kpass1(const float* __restrict__ x,
                                                 const float* __restrict__ W,
                                                 float* __restrict__ partial)
{
  __shared__ float4 smem4[TOT4 + XTOT4];   // 37888 B
  float4* Wl = smem4;
  float4* Xl = smem4 + TOT4;
  const int tid  = threadIdx.x;
  const int lane = tid & 63;
  const int wv   = __builtin_amdgcn_readfirstlane(tid >> 6);
  const int eh   = lane & 7;       // e-half slot: e in {eh, eh+8}
  const int bs   = lane >> 3;      // b slot: b_off = 8k + bs
  const int h    = wv >> 1;        // b half (32 b's each)
  const int p    = wv & 1;         // n parity
  const int nb0  = blockIdx.x * NBT;

  const int sA0 = (eh*2)       ^ ((eh*2)>>3);
  const int sB0 = (eh*2+1)     ^ ((eh*2+1)>>3);
  const int sA1 = ((eh+8)*2)   ^ (((eh+8)*2)>>3);
  const int sB1 = ((eh+8)*2+1) ^ (((eh+8)*2+1)>>3);

  stageWX(W, x, nb0, blockIdx.y*64, tid, Wl, Xl);
  __syncthreads();

  const float4* Xr = Xl + (h*32 + bs)*XROW;   // k-th b adds 8*XROW
  float aJ0E0[4]={0,0,0,0}, aJ0E1[4]={0,0,0,0}, aJ1E0[4]={0,0,0,0}, aJ1E1[4]={0,0,0,0};
  #pragma unroll 1
  for (int ni=p; ni<NBT; ni+=2){
    const float4 w00a = Wl[ni*32 + sA0],       w00b = Wl[ni*32 + sB0];       // j0 e0
    const float4 w01a = Wl[ni*32 + sA1],       w01b = Wl[ni*32 + sB1];       // j0 e1
    const float4 w10a = Wl[(NBT+ni)*32 + sA0], w10b = Wl[(NBT+ni)*32 + sB0]; // j1 e0
    const float4 w11a = Wl[(NBT+ni)*32 + sA1], w11b = Wl[(NBT+ni)*32 + sB1]; // j1 e1
    #pragma unroll
    for (int k=0;k<4;++k){
      const float4 xa = Xr[k*(8*XROW) + ni*2];
      const float4 xb = Xr[k*(8*XROW) + ni*2 + 1];
      aJ0E0[k] = dot8(w00a,w00b, xa,xb, aJ0E0[k]);
      aJ0E1[k] = dot8(w01a,w01b, xa,xb, aJ0E1[k]);
      aJ1E0[k] = dot8(w10a,w10b, xa,xb, aJ1E0[k]);
      aJ1E1[k] = dot8(w11a,w11b, xa,xb, aJ1E1[k]);
    }
  }

  // n-parity merge: odd waves publish, even waves combine + store.
  __syncthreads();
  float* red = (float*)smem4;      // [h][32 b][33]: 2112 f32, overlays W tile
  if (p == 1){
    #pragma unroll
    for (int k=0;k<4;++k){
      const int base = h*1056 + (8*k+bs)*33 + eh;
      red[base]      = aJ0E0[k];
      red[base + 8]  = aJ0E1[k];
      red[base + 16] = aJ1E0[k];
      red[base + 24] = aJ1E1[k];
    }
  }
  __syncthreads();
  if (p == 0){
    float* dst = partial + (size_t)(blockIdx.x*4 + blockIdx.y)*2048;
    #pragma unroll
    for (int k=0;k<4;++k){
      const int base = h*1056 + (8*k+bs)*33 + eh;
      const int go   = (h*32 + 8*k + bs)*32 + eh;
      dst[go]      = aJ0E0[k] + red[base];
      dst[go + 8]  = aJ0E1[k] + red[base + 8];
      dst[go + 16] = aJ1E0[k] + red[base + 16];
      dst[go + 24] = aJ1E1[k] + red[base + 24];
    }
  }
}

__global__ __launch_bounds__(256, 3) void kpass2(const float* __restrict__ x,
                                                 const float* __restrict__ W,
                                                 const float* __restrict__ v1,
                                                 float* __restrict__ partial)
{
  __shared__ float4 smem4[TOT4 + XTOT4];
  float4* Wl = smem4;
  float4* Xl = smem4 + TOT4;
  const int tid  = threadIdx.x;
  const int lane = tid & 63;
  const int wv   = __builtin_amdgcn_readfirstlane(tid >> 6);
  const int eh   = lane & 7;
  const int bs   = lane >> 3;
  const int h    = wv >> 1;
  const int p    = wv & 1;
  const int nb0  = blockIdx.x * NBT;
  const int b0g  = blockIdx.y*64;

  const int sA0 = (eh*2)       ^ ((eh*2)>>3);
  const int sB0 = (eh*2+1)     ^ ((eh*2+1)>>3);
  const int sA1 = ((eh+8)*2)   ^ (((eh+8)*2)>>3);
  const int sB1 = ((eh+8)*2+1) ^ (((eh+8)*2+1)>>3);

  stageWX(W, x, nb0, b0g, tid, Wl, Xl);
  // routing vector v1[b][j*16+e] for this thread's 4 b's x 2 j x 2 e
  float v00[4], v01[4], v10[4], v11[4];   // [jE]: j, e-half
  #pragma unroll
  for (int k=0;k<4;++k){
    const size_t vb = (size_t)(b0g + h*32 + 8*k + bs)*32 + eh;
    v00[k] = v1[vb];        // j0 e0
    v01[k] = v1[vb + 8];    // j0 e1
    v10[k] = v1[vb + 16];   // j1 e0
    v11[k] = v1[vb + 24];   // j1 e1
  }
  __syncthreads();

  const float4* Xr = Xl + (h*32 + bs)*XROW;
  float aJ0E0[4]={0,0,0,0}, aJ0E1[4]={0,0,0,0}, aJ1E0[4]={0,0,0,0}, aJ1E1[4]={0,0,0,0};
  #pragma unroll 1
  for (int ni=p; ni<NBT; ni+=2){
    const float4 w00a = Wl[ni*32 + sA0],       w00b = Wl[ni*32 + sB0];
    const float4 w01a = Wl[ni*32 + sA1],       w01b = Wl[ni*32 + sB1];
    const float4 w10a = Wl[(NBT+ni)*32 + sA0], w10b = Wl[(NBT+ni)*32 + sB0];
    const float4 w11a = Wl[(NBT+ni)*32 + sA1], w11b = Wl[(NBT+ni)*32 + sB1];
    #pragma unroll
    for (int k=0;k<4;++k){
      const float4 xa = Xr[k*(8*XROW) + ni*2];
      const float4 xb = Xr[k*(8*XROW) + ni*2 + 1];
      const float u00 = dot8(w00a,w00b, xa,xb, 0.f);
      const float u01 = dot8(w01a,w01b, xa,xb, 0.f);
      const float u10 = dot8(w10a,w10b, xa,xb, 0.f);
      const float u11 = dot8(w11a,w11b, xa,xb, 0.f);
      // delta = l1 - l0 over all 16 e: in-thread 2e + 8-lane DPP
      float t = v10[k]*u10;
      t = fmaf(v11[k], u11, t);
      t = fmaf(-v00[k], u00, t);
      t = fmaf(-v01[k], u01, t);
      t = dpp_add8(t);
      const float c0 = __builtin_amdgcn_rcpf(1.f + __expf(t));   // softmax over 2 caps
      const float c1 = 1.f - c0;
      aJ0E0[k] = fmaf(c0, u00, aJ0E0[k]);
      aJ0E1[k] = fmaf(c0, u01, aJ0E1[k]);
      aJ1E0[k] = fmaf(c1, u10, aJ1E0[k]);
      aJ1E1[k] = fmaf(c1, u11, aJ1E1[k]);
    }
  }

  __syncthreads();
  float* red = (float*)smem4;
  if (p == 1){
    #pragma unroll
    for (int k=0;k<4;++k){
      const int base = h*1056 + (8*k+bs)*33 + eh;
      red[base]      = aJ0E0[k];
      red[base + 8]  = aJ0E1[k];
      red[base + 16] = aJ1E0[k];
      red[base + 24] = aJ1E1[k];
    }
  }
  __syncthreads();
  if (p == 0){
    float* dst = partial + (size_t)(blockIdx.x*4 + blockIdx.y)*2048;
    #pragma unroll
    for (int k=0;k<4;++k){
      const int base = h*1056 + (8*k+bs)*33 + eh;
      const int go   = (h*32 + 8*k + bs)*32 + eh;
      dst[go]      = aJ0E0[k] + red[base];
      dst[go + 8]  = aJ0E1[k] + red[base + 8];
      dst[go + 16] = aJ1E0[k] + red[base + 16];
      dst[go + 24] = aJ1E1[k] + red[base + 24];
    }
  }
}

// Fused reduce (sum CGX chunk-partials, split-K by 2) + squash.
// grid 64 x 256: tid&127 -> output within block's 128, tid>>7 -> K-half.
template<bool HALF>
__global__ __launch_bounds__(256) void kred(const float* __restrict__ partial,
                                            float* __restrict__ dst)
{
  __shared__ float sh[128];
  const int tid  = threadIdx.x;
  const int o    = blockIdx.x*128 + (tid & 127);   // 64*128 = 8192 outputs
  const int half = tid >> 7;
  const int btile = o >> 11, q = o & 2047;
  const float* p = partial + (size_t)btile*2048 + q + (size_t)half*(CGX/2)*8192;
  float s = 0.f;
  #pragma unroll 24
  for (int cx=0; cx<CGX/2; ++cx) s += p[(size_t)cx*8192];
  if (half) sh[tid & 127] = s;
  __syncthreads();
  if (!half){
    s += sh[tid & 127];
    if (HALF) s *= 0.5f;
    float n2 = s*s;
    #pragma unroll
    for (int m=1; m<16; m<<=1) n2 += __shfl_xor(n2, m);
    dst[o] = s * (n2/(1.f+n2)) * rsqrtf(n2 + 1e-9f);
  }
}

// ---------------- fallback: monolithic (no ws) ----------------
#define NT 512
__global__ __launch_bounds__(NT) void kmono(const float* __restrict__ x,
                                            const float* __restrict__ W,
                                            float* __restrict__ out)
{
  const int b    = blockIdx.x;
  const int tid  = threadIdx.x;
  const int wv   = tid >> 6;
  const int lane = tid & 63;
  __shared__ float wred[8*33];
  __shared__ float vsh[32];

  float acc[32];
  #pragma unroll
  for (int i=0;i<32;++i) acc[i]=0.f;
  for (int n = tid; n < N_; n += NT){
    const float4 xa = *(const float4*)(x + ((size_t)b*N_ + n)*D_);
    const float4 xb = *(const float4*)(x + ((size_t)b*N_ + n)*D_ + 4);
    #pragma unroll
    for (int j=0;j<J_;++j){
      const float* wp = W + ((size_t)j*N_ + n)*(E_*D_);
      #pragma unroll
      for (int e=0;e<E_;++e){
        const float4 wa = *(const float4*)(wp + e*8);
        const float4 wb = *(const float4*)(wp + e*8 + 4);
        float a = acc[j*16+e];
        a = fmaf(wa.x,xa.x,a); a = fmaf(wa.y,xa.y,a); a = fmaf(wa.z,xa.z,a); a = fmaf(wa.w,xa.w,a);
        a = fmaf(wb.x,xb.x,a); a = fmaf(wb.y,xb.y,a); a = fmaf(wb.z,xb.z,a); a = fmaf(wb.w,xb.w,a);
        acc[j*16+e] = a;
      }
    }
  }
  #pragma unroll
  for (int i=0;i<32;++i){
    float v = acc[i];
    #pragma unroll
    for (int off=32; off; off>>=1) v += __shfl_xor(v, off);
    acc[i] = v;
  }
  if (lane == 0){
    #pragma unroll
    for (int i=0;i<32;++i) wred[wv*33 + i] = acc[i];
  }
  __syncthreads();
  if (tid < 32){
    float s = 0.f;
    #pragma unroll
    for (int w=0;w<8;++w) s += wred[w*33 + tid];
    wred[tid] = 0.5f * s;
  }
  __syncthreads();
  if (tid < 32){
    const int j = tid >> 4; float n2 = 0.f;
    #pragma unroll
    for (int e=0;e<16;++e){ const float sv = wred[j*16+e]; n2 = fmaf(sv,sv,n2); }
    vsh[tid] = wred[tid] * (n2/(1.f+n2)) * rsqrtf(n2 + 1e-9f);
  }
  __syncthreads();
  float vv[32];
  #pragma unroll
  for (int i=0;i<32;++i) vv[i] = vsh[i];

  #pragma unroll
  for (int i=0;i<32;++i) acc[i]=0.f;
  for (int n = tid; n < N_; n += NT){
    const float4 xa = *(const float4*)(x + ((size_t)b*N_ + n)*D_);
    const float4 xb = *(const float4*)(x + ((size_t)b*N_ + n)*D_ + 4);
    float u[32];
    #pragma unroll
    for (int j=0;j<J_;++j){
      const float* wp = W + ((size_t)j*N_ + n)*(E_*D_);
      #pragma unroll
      for (int e=0;e<E_;++e){
        const float4 wa = *(const float4*)(wp + e*8);
        const float4 wb = *(const float4*)(wp + e*8 + 4);
        float a;
        a = wa.x*xa.x; a = fmaf(wa.y,xa.y,a); a = fmaf(wa.z,xa.z,a); a = fmaf(wa.w,xa.w,a);
        a = fmaf(wb.x,xb.x,a); a = fmaf(wb.y,xb.y,a); a = fmaf(wb.z,xb.z,a); a = fmaf(wb.w,xb.w,a);
        u[j*16+e] = a;
      }
    }
    float l0=0.f, l1=0.f;
    #pragma unroll
    for (int e=0;e<16;++e){ l0 = fmaf(vv[e],u[e],l0); l1 = fmaf(vv[16+e],u[16+e],l1); }
    const float c0 = 1.f/(1.f + __expf(l1 - l0));
    const float c1 = 1.f - c0;
    #pragma unroll
    for (int e=0;e<16;++e){ acc[e] = fmaf(c0,u[e],acc[e]); acc[16+e] = fmaf(c1,u[16+e],acc[16+e]); }
  }
  #pragma unroll
  for (int i=0;i<32;++i){
    float v = acc[i];
    #pragma unroll
    for (int off=32; off; off>>=1) v += __shfl_xor(v, off);
    acc[i] = v;
  }
  __syncthreads();
  if (lane == 0){
    #pragma unroll
    for (int i=0;i<32;++i) wred[wv*33 + i] = acc[i];
  }
  __syncthreads();
  if (tid < 32){
    float s = 0.f;
    #pragma unroll
    for (int w=0;w<8;++w) s += wred[w*33 + tid];
    wred[tid] = s;
  }
  __syncthreads();
  if (tid < 32){
    const int j = tid >> 4; float n2 = 0.f;
    #pragma unroll
    for (int e=0;e<16;++e){ const float sv = wred[j*16+e]; n2 = fmaf(sv,sv,n2); }
    out[(size_t)b*32 + tid] = wred[tid] * (n2/(1.f+n2)) * rsqrtf(n2 + 1e-9f);
  }
}

extern "C" void kernel_launch(void* const* d_in, const int* in_sizes, int n_in,
                              void* d_out, int out_size, void* d_ws, size_t ws_size,
                              hipStream_t stream)
{
  const float* x = (const float*)d_in[0];   // [256,6912,8]
  const float* W = (const float*)d_in[1];   // [2,6912,16,8]
  if (n_in >= 2 && in_sizes[0] < in_sizes[1]){
    x = (const float*)d_in[1]; W = (const float*)d_in[0];
  }
  float* out = (float*)d_out;               // fp32 [256,2,16]

  const size_t need = (size_t)(8192 + (size_t)CGX*4*2048) * sizeof(float);  // ~18.9 MB

  if (ws_size >= need){
    float* wsf     = (float*)d_ws;
    float* v1      = wsf;           // 8192 floats
    float* partial = wsf + 8192;    // CGX*4*2048 floats
    kpass1<<<dim3(CGX,4), 256, 0, stream>>>(x, W, partial);
    kred<true ><<<64, 256, 0, stream>>>(partial, v1);
    kpass2<<<dim3(CGX,4), 256, 0, stream>>>(x, W, v1, partial);
    kred<false><<<64, 256, 0, stream>>>(partial, out);
  } else {
    kmono<<<B_, NT, 0, stream>>>(x, W, out);
  }
}